// Round 8
// baseline (63.748 us; speedup 1.0000x reference)
//
#include <hip/hip_runtime.h>

#define S_TOTAL (512 * 512)     // 262144
#define BATCH 64
#define KTOT2 16384             // 128 ty * 128 j  (fully folded K)
#define NBLK_ZA 64

typedef float vfloat4 __attribute__((ext_vector_type(4)));
typedef float vfloat2 __attribute__((ext_vector_type(2)));

// ds_swizzle xor helpers (imm must be literal). BitMode: (xor<<10)|0x1f.
__device__ __forceinline__ float swz_x1(float v) {
    return __int_as_float(__builtin_amdgcn_ds_swizzle(__float_as_int(v), 0x041F));
}
__device__ __forceinline__ float swz_x2(float v) {
    return __int_as_float(__builtin_amdgcn_ds_swizzle(__float_as_int(v), 0x081F));
}
__device__ __forceinline__ float swz_x4(float v) {
    return __int_as_float(__builtin_amdgcn_ds_swizzle(__float_as_int(v), 0x101F));
}
__device__ __forceinline__ float swz_x8(float v) {
    return __int_as_float(__builtin_amdgcn_ds_swizzle(__float_as_int(v), 0x201F));
}

// ---------------------------------------------------------------------------
// pass1 (fused): A -> B2.  B2[nr,ty,j] = sum_y wy(y,ty) sum_x wx(x,j) A[nr,y,x]
// Block = (nr, ty-chunk of 4). x-fold reads 3 overlapping float4 windows
// DIRECTLY from global (within-wave overlap -> L1 hits; no A staging, 10 KB
// LDS -> 8 blocks/CU). Zero rows outside [0,512); edge corrections match the
// proven folded form exactly.
// ---------------------------------------------------------------------------
__global__ __launch_bounds__(256) void adjxy_kernel(
    const float* __restrict__ A,      // (20, 512, 512)
    float* __restrict__ B2)           // (20, 128, 128)
{
    __shared__ float b1loc[20][128];  // 10 KB

    const int t  = threadIdx.x;
    const int nr = blockIdx.x >> 5;   // 0..19
    const int tc = blockIdx.x & 31;   // ty-chunk 0..31
    const int y0 = 16 * tc - 2;       // global y of local row 0

    const float* An = A + (size_t)nr * S_TOTAL;

    // ---- x-fold straight from global: b1loc[rl][j]
#pragma unroll
    for (int i = t; i < 20 * 128; i += 256) {
        const int rl = i >> 7;
        const int j  = i & 127;
        const int y  = y0 + rl;
        float s = 0.0f;
        if (y >= 0 && y < 512) {
            const float* Ay = An + (size_t)y * 512;
            const int base = 4 * j;
            const vfloat4 m0 = *(const vfloat4*)(Ay + max(base - 4, 0));
            const vfloat4 m1 = *(const vfloat4*)(Ay + base);
            const vfloat4 m2 = *(const vfloat4*)(Ay + min(base + 4, 508));
            // window 4j-2..4j+5 = m0.z, m0.w, m1.xyzw, m2.x, m2.y
            float e0 = m0.z, e1 = m0.w, e6 = m2.x, e7 = m2.y;
            if (j == 0)   { e0 = 0.0f; e1 = 0.0f; }
            if (j == 127) { e6 = 0.0f; e7 = 0.0f; }
            s = 0.125f * e0 + 0.375f * e1
              + 0.625f * m1.x + 0.875f * m1.y
              + 0.875f * m1.z + 0.625f * m1.w
              + 0.375f * e6 + 0.125f * e7;
            if (j == 0)   s += 0.375f * Ay[0]   + 0.125f * Ay[1];
            if (j == 127) s += 0.125f * Ay[510] + 0.375f * Ay[511];
        }
        b1loc[rl][j] = s;
    }
    __syncthreads();

    // ---- y-fold: B2[ty][j] = sum_p wy[p] * b1loc[4*tyl+p][j] (+ edges)
    const float w[8] = {0.125f, 0.375f, 0.625f, 0.875f,
                        0.875f, 0.625f, 0.375f, 0.125f};
#pragma unroll
    for (int i = t; i < 512; i += 256) {
        const int tyl = i >> 7;
        const int j   = i & 127;
        const int ty  = tc * 4 + tyl;
        float s = 0.0f;
#pragma unroll
        for (int p = 0; p < 8; ++p)
            s = fmaf(w[p], b1loc[4 * tyl + p][j], s);
        if (ty == 0)   s += 0.375f * b1loc[2][j]  + 0.125f * b1loc[3][j];   // y=0,1
        if (ty == 127) s += 0.125f * b1loc[16][j] + 0.375f * b1loc[17][j];  // y=510,511
        B2[(size_t)nr * KTOT2 + ty * 128 + j] = s;
    }
}

// ---------------------------------------------------------------------------
// pass2: za partials = B2 (20 x 16384) . x^T (64 x 16384), PLUS the final
// cross-block reduce + z recurrence done by the last-finishing block
// (deterministic ticket pattern: fence -> barrier -> t0 atomicAdd).
// ---------------------------------------------------------------------------
__global__ __launch_bounds__(512) void za_partial_kernel(
    const float* __restrict__ x,      // (64, 16384)
    const float* __restrict__ B2,     // (20, 16384)
    float* __restrict__ partial,      // (64, 1280) elem b*20+nr
    float* __restrict__ zg,           // (256,) = z[b*4+r]
    unsigned int* __restrict__ counter)
{
    __shared__ float za_lds[1280];
    __shared__ unsigned int ticket;

    const int t    = threadIdx.x;
    const int blk  = blockIdx.x;
    const int w    = t >> 6;
    const int lane = t & 63;
    const int b0   = w * 8;
    const size_t kbase = (size_t)blk * 256 + 4 * lane;

    vfloat4 xv[8];
#pragma unroll
    for (int bi = 0; bi < 8; ++bi)
        xv[bi] = *(const vfloat4*)(x + (size_t)(b0 + bi) * KTOT2 + kbase);

    float* pb = partial + (size_t)blk * 1280;
    const int lane1 = lane & 1, lane2 = lane & 2, lane4 = lane & 4, lane8 = lane & 8;

#pragma unroll
    for (int ch = 0; ch < 2; ++ch) {
        float acc[16][5];
#pragma unroll
        for (int v = 0; v < 16; ++v)
#pragma unroll
            for (int tt = 0; tt < 5; ++tt) acc[v][tt] = 0.0f;

#pragma unroll
        for (int tt = 0; tt < 5; ++tt)
#pragma unroll
            for (int par = 0; par < 2; ++par) {
                const int nr = ch * 10 + 2 * tt + par;
                const vfloat4 bq = *(const vfloat4*)(B2 + (size_t)nr * KTOT2 + kbase);
#pragma unroll
                for (int bi = 0; bi < 8; ++bi) {
                    acc[bi * 2 + par][tt] =
                        fmaf(bq.x, xv[bi].x, fmaf(bq.y, xv[bi].y,
                        fmaf(bq.z, xv[bi].z, fmaf(bq.w, xv[bi].w,
                             acc[bi * 2 + par][tt]))));
                }
            }

        float s1[8][5];
#pragma unroll
        for (int v = 0; v < 8; ++v)
#pragma unroll
            for (int tt = 0; tt < 5; ++tt) {
                const float u = acc[v][tt], h = acc[v + 8][tt];
                s1[v][tt] = (lane1 ? h : u) + swz_x1(lane1 ? u : h);
            }
        float s2[4][5];
#pragma unroll
        for (int v = 0; v < 4; ++v)
#pragma unroll
            for (int tt = 0; tt < 5; ++tt) {
                const float u = s1[v][tt], h = s1[v + 4][tt];
                s2[v][tt] = (lane2 ? h : u) + swz_x2(lane2 ? u : h);
            }
        float s3[2][5];
#pragma unroll
        for (int v = 0; v < 2; ++v)
#pragma unroll
            for (int tt = 0; tt < 5; ++tt) {
                const float u = s2[v][tt], h = s2[v + 2][tt];
                s3[v][tt] = (lane4 ? h : u) + swz_x4(lane4 ? u : h);
            }
        float s4[5];
#pragma unroll
        for (int tt = 0; tt < 5; ++tt) {
            const float u = s3[0][tt], h = s3[1][tt];
            s4[tt] = (lane8 ? h : u) + swz_x8(lane8 ? u : h);
        }
#pragma unroll
        for (int tt = 0; tt < 5; ++tt) {
            s4[tt] += __shfl_xor(s4[tt], 16, 64);
            s4[tt] += __shfl_xor(s4[tt], 32, 64);
        }

        if (lane < 16) {
            const int m = ((lane & 1) << 3) | ((lane & 2) << 1) |
                          ((lane & 4) >> 1) | ((lane & 8) >> 3);
            float* dst = pb + (b0 + (m >> 1)) * 20 + ch * 10 + (m & 1);
#pragma unroll
            for (int tt = 0; tt < 5; ++tt) dst[2 * tt] = s4[tt];
        }
    }

    // ---- last-block-done: reduce partials -> za -> z
    __threadfence();                  // make this block's partial visible
    __syncthreads();
    if (t == 0) ticket = atomicAdd(counter, 1u);
    __syncthreads();
    if (ticket != NBLK_ZA - 1) return;

    __threadfence();                  // acquire all blocks' partials
    for (int c = t; c < 1280; c += 512) {
        float a0 = 0, a1 = 0, a2 = 0, a3 = 0;
        for (int r = 0; r < NBLK_ZA; r += 4) {
            a0 += partial[(size_t)(r + 0) * 1280 + c];
            a1 += partial[(size_t)(r + 1) * 1280 + c];
            a2 += partial[(size_t)(r + 2) * 1280 + c];
            a3 += partial[(size_t)(r + 3) * 1280 + c];
        }
        za_lds[c] = (a0 + a1) + (a2 + a3);
    }
    __syncthreads();
    if (t < 64) {
#pragma unroll
        for (int r = 0; r < 4; ++r) {
            float zv = za_lds[t * 20 + r];              // n = 0
#pragma unroll
            for (int n = 1; n < 5; ++n)
                zv *= (1.0f + za_lds[t * 20 + n * 4 + r]);
            zg[t * 4 + r] = zv;
        }
    }
}

// ---------------------------------------------------------------------------
// pass3: out = z*C^T + bias. 512 blocks x 256 thr, thread owns an s-pair,
// full batch per block (C read exactly once). float2 NT stores.
// ---------------------------------------------------------------------------
__global__ __launch_bounds__(256) void out_kernel(
    const float* __restrict__ C,      // (S,4)
    const float* __restrict__ bias,   // (S,)
    const float* __restrict__ zg,     // (256,) z[b*4+r]
    float* __restrict__ out)          // (64,S)
{
    __shared__ float zs[256];
    const int t = threadIdx.x;
    zs[t] = zg[t];
    __syncthreads();

    const int s0 = (blockIdx.x * 256 + t) * 2;
    const vfloat4 c0 = *(const vfloat4*)(C + (size_t)s0 * 4);
    const vfloat4 c1 = *(const vfloat4*)(C + (size_t)s0 * 4 + 4);
    const vfloat2 bv = *(const vfloat2*)(bias + s0);

#pragma unroll 8
    for (int bb = 0; bb < BATCH; ++bb) {
        const float z0 = zs[bb * 4 + 0], z1 = zs[bb * 4 + 1];
        const float z2 = zs[bb * 4 + 2], z3 = zs[bb * 4 + 3];
        vfloat2 o;
        o.x = fmaf(z0, c0.x, fmaf(z1, c0.y, fmaf(z2, c0.z, fmaf(z3, c0.w, bv.x))));
        o.y = fmaf(z0, c1.x, fmaf(z1, c1.y, fmaf(z2, c1.z, fmaf(z3, c1.w, bv.y))));
        __builtin_nontemporal_store(o, (vfloat2*)(out + (size_t)bb * S_TOTAL + s0));
    }
}

// ---------------------------------------------------------------------------
extern "C" void kernel_launch(void* const* d_in, const int* in_sizes, int n_in,
                              void* d_out, int out_size, void* d_ws, size_t ws_size,
                              hipStream_t stream)
{
    const float* x    = (const float*)d_in[0];
    const float* A    = (const float*)d_in[1];
    const float* C    = (const float*)d_in[2];
    const float* bias = (const float*)d_in[3];
    float* out = (float*)d_out;

    float* B2      = (float*)d_ws;                        // 20*16384 = 1.31 MB
    float* partial = B2 + (size_t)20 * KTOT2;             // 64*1280
    float* zg      = partial + (size_t)NBLK_ZA * 1280;    // 256
    unsigned int* counter = (unsigned int*)(zg + 256);

    hipMemsetAsync(counter, 0, sizeof(unsigned int), stream);
    adjxy_kernel<<<640, 256, 0, stream>>>(A, B2);
    za_partial_kernel<<<NBLK_ZA, 512, 0, stream>>>(x, B2, partial, zg, counter);
    out_kernel<<<512, 256, 0, stream>>>(C, bias, zg, out);
}